// Round 12
// baseline (39.834 us; speedup 1.0000x reference)
//
#include <hip/hip_runtime.h>
#include <hip/hip_bf16.h>
#include <math.h>

#define N_ROWS 8192
#define N_HALF 4096
#define D 128
#define SEGS 8
#define IBLKS (N_ROWS / 128)            // 64 i-tiles of 128 rows
#define SEGCOLS (N_ROWS / SEGS)         // 1024 cols per block
#define HALVES (SEGCOLS / 64)           // 16 halves of 64 cols
// scale = sqrt(2 * log2(e)): zq_i . zq_j = 2*log2(e)*cos -> exp2(dot) = exp(2*cos)
#define ZSCALE 1.6986437717f
#define LN2 0.69314718056f

typedef __attribute__((ext_vector_type(8))) int   i32x8;   // 32B fp8 fragment
typedef __attribute__((ext_vector_type(4))) int   i32x4;
typedef __attribute__((ext_vector_type(4))) float f32x4;

__device__ __forceinline__ float fast_exp2(float x) {
#if __has_builtin(__builtin_amdgcn_exp2f)
    return __builtin_amdgcn_exp2f(x);
#else
    return exp2f(x);
#endif
}

// ---------------- kernel 1: normalize rows; emit scaled fp8 e4m3 z ----------------
__global__ __launch_bounds__(256) void normalize_kernel(
    const float* __restrict__ p1, const float* __restrict__ p2,
    unsigned char* __restrict__ zq)
{
    const int row = blockIdx.x * 4 + (threadIdx.x >> 6);
    const int lane = threadIdx.x & 63;
    const float* src = (row < N_HALF) ? (p1 + (size_t)row * D)
                                      : (p2 + (size_t)(row - N_HALF) * D);
    float2 v = ((const float2*)src)[lane];
    float ss = v.x * v.x + v.y * v.y;
    #pragma unroll
    for (int m = 1; m < 64; m <<= 1) ss += __shfl_xor(ss, m);
    float inv = ZSCALE / fmaxf(sqrtf(ss), 1e-12f);
    // pack 2 fp8 (RNE, OCP e4m3): byte0 = k=2*lane, byte1 = k=2*lane+1
    int pk = __builtin_amdgcn_cvt_pk_fp8_f32(v.x * inv, v.y * inv, 0, false);
    ((ushort*)(zq + (size_t)row * D))[lane] = (ushort)(pk & 0xFFFF);
}

// ---------------- kernel 2: 3-buffer 2-deep DMA pipeline + MX-fp8 K=128 MFMA Gram ----------------
// Wave-private staging/reads (no main-loop barriers). Half-buffer = 64 cols x
// 128 B = 512 slots of 16B. Slot s: col r = s>>3, chunk c = (s&7)^(r&7).
// Read (col cB, quarter lh): 32B = chunks {2lh, 2lh+1} (same XOR pair).
__global__ __launch_bounds__(256, 3) void simloss_mfma(
    const unsigned char* __restrict__ zq, float* __restrict__ partial,
    float* __restrict__ posv)
{
    __shared__ unsigned char Bs[3][64 * 128];   // 3 x 8 KB
    __shared__ float red[128][4];
    const int t = threadIdx.x;
    const int w = t >> 6;                // wave 0..3 -> 16-col slice of each half
    const int l = t & 63;
    const int l15 = l & 15, lh = l >> 4;
    const int bi = blockIdx.x & (IBLKS - 1);
    const int seg = blockIdx.x >> 6;
    const int iBase = bi * 128;
    const int segBase = seg * SEGCOLS;
    const int pBase = iBase ^ N_HALF;    // partner tile base (128-aligned)

// stage this wave's 16-col slice of one 64x128B half: 2 DMA issues.
#define STAGE(buf, jB)                                                          \
    {                                                                           \
        _Pragma("unroll")                                                       \
        for (int i = 0; i < 2; ++i) {                                           \
            const int s = w * 128 + i * 64 + l;                                 \
            const int r = s >> 3;                                               \
            const int c = (s & 7) ^ (r & 7);                                    \
            const unsigned char* g = zq + (size_t)((jB) + r) * D + c * 16;      \
            unsigned char* lp = (buf) + (size_t)s * 16;                         \
            __builtin_amdgcn_global_load_lds(                                   \
                (const __attribute__((address_space(1))) unsigned int*)g,       \
                (__attribute__((address_space(3))) unsigned int*)lp, 16, 0, 0); \
        }                                                                       \
    }

    STAGE(&Bs[0][0], segBase);           // prologue: halves 0,1 in flight
    STAGE(&Bs[1][0], segBase + 64);

    // A tile (128 rows x 128 k fp8) in registers: 8 m-tiles x 32 B
    i32x8 a[8];
    #pragma unroll
    for (int m = 0; m < 8; ++m)
        a[m] = *(const i32x8*)(zq + (size_t)(iBase + m * 16 + l15) * D + lh * 32);

    float rs[8][4];
    #pragma unroll
    for (int m = 0; m < 8; ++m)
        #pragma unroll
        for (int r = 0; r < 4; ++r) rs[m][r] = 0.0f;

    const int cB = w * 16 + l15;         // this lane's col within each half
    const int slot0base = cB * 8;

    int bufIdx = 0;                      // rotating buffer index (0,1,2)
    #pragma unroll 1
    for (int h = 0; h < HALVES; ++h) {
        const int jBase = segBase + h * 64;
        const unsigned char* bufc = &Bs[bufIdx][0];
        const int nextBuf = (bufIdx + 2 >= 3) ? bufIdx - 1 : bufIdx + 2;

        if (h + 2 < HALVES) {
            STAGE(&Bs[nextBuf][0], jBase + 128);             // h+2 in flight
            asm volatile("s_waitcnt vmcnt(4)" ::: "memory"); // h landed (h+1,h+2 fly)
        } else if (h + 1 < HALVES) {
            asm volatile("s_waitcnt vmcnt(2)" ::: "memory"); // h landed (h+1 flies)
        } else {
            asm volatile("s_waitcnt vmcnt(0)" ::: "memory");
        }

        const int slot0 = slot0base + ((2 * lh)     ^ (cB & 7));
        const int slot1 = slot0base + ((2 * lh + 1) ^ (cB & 7));
        i32x4 blo = *(const i32x4*)(bufc + slot0 * 16);
        i32x4 bhi = *(const i32x4*)(bufc + slot1 * 16);
        i32x8 bv;
        bv[0] = blo[0]; bv[1] = blo[1]; bv[2] = blo[2]; bv[3] = blo[3];
        bv[4] = bhi[0]; bv[5] = bhi[1]; bv[6] = bhi[2]; bv[7] = bhi[3];

        f32x4 c[8];
        #pragma unroll
        for (int m = 0; m < 8; ++m) { f32x4 z4 = {0.f, 0.f, 0.f, 0.f}; c[m] = z4; }
        #pragma unroll
        for (int m = 0; m < 8; ++m)
            c[m] = __builtin_amdgcn_mfma_scale_f32_16x16x128_f8f6f4(
                       a[m], bv, c[m], 0, 0,           // cbsz=FP8, blgp=FP8
                       0, 0x7F7F7F7Fu,                 // scale A = 2^0
                       0, 0x7F7F7F7Fu);                // scale B = 2^0

        if ((jBase & ~127) == iBase) {   // rare: half covers self-diagonal
            const int sOff = jBase - iBase;          // 0 or 64
            #pragma unroll
            for (int m = 0; m < 8; ++m)
                #pragma unroll
                for (int r = 0; r < 4; ++r) {
                    const int rowLocal = m * 16 + lh * 4 + r;
                    float e = fast_exp2(c[m][r]);
                    rs[m][r] += (rowLocal == sOff + cB) ? 0.0f : e;
                }
        } else {                         // hot path
            #pragma unroll
            for (int m = 0; m < 8; ++m)
                #pragma unroll
                for (int r = 0; r < 4; ++r)
                    rs[m][r] += fast_exp2(c[m][r]);
        }
        if ((jBase & ~127) == pBase) {   // rare: half covers partner diagonal
            const int pOff = jBase - pBase;          // 0 or 64
            #pragma unroll
            for (int m = 0; m < 8; ++m)
                #pragma unroll
                for (int r = 0; r < 4; ++r) {
                    const int rowLocal = m * 16 + lh * 4 + r;
                    if (rowLocal == pOff + cB)
                        posv[iBase + rowLocal] = c[m][r] * LN2;   // = 2*cos
                }
        }

        bufIdx = (bufIdx + 1 >= 3) ? 0 : bufIdx + 1;
    }
#undef STAGE

    // reduce rs over the 16 cols held across l15 lanes
    #pragma unroll
    for (int m = 0; m < 8; ++m)
        #pragma unroll
        for (int r = 0; r < 4; ++r) {
            float v = rs[m][r];
            v += __shfl_xor(v, 1); v += __shfl_xor(v, 2);
            v += __shfl_xor(v, 4); v += __shfl_xor(v, 8);
            rs[m][r] = v;
        }
    if (l15 == 0) {
        #pragma unroll
        for (int m = 0; m < 8; ++m)
            #pragma unroll
            for (int r = 0; r < 4; ++r)
                red[m * 16 + lh * 4 + r][w] = rs[m][r];
    }
    __syncthreads();                     // real cross-wave reduce: keep
    if (t < 128) {
        float v = red[t][0] + red[t][1] + red[t][2] + red[t][3];
        partial[(size_t)seg * N_ROWS + iBase + t] = v;
    }
}

// ---------------- kernel 3: per-row loss + per-block deterministic sum ----------------
__global__ __launch_bounds__(256) void rowloss_kernel(
    const float* __restrict__ partial, const float* __restrict__ posv,
    float* __restrict__ bsum)
{
    const int row = blockIdx.x * 256 + threadIdx.x;
    float denom = 0.0f;
    #pragma unroll
    for (int s = 0; s < SEGS; ++s) denom += partial[(size_t)s * N_ROWS + row];
    float loss = logf(denom) - posv[row];
    #pragma unroll
    for (int m = 1; m < 64; m <<= 1) loss += __shfl_xor(loss, m);
    __shared__ float red[4];
    if ((threadIdx.x & 63) == 0) red[threadIdx.x >> 6] = loss;
    __syncthreads();
    if (threadIdx.x == 0) bsum[blockIdx.x] = red[0] + red[1] + red[2] + red[3];
}

// ---------------- kernel 4: final reduce of 32 block sums ----------------
__global__ __launch_bounds__(64) void final_reduce(
    const float* __restrict__ bsum, float* __restrict__ out)
{
    const int t = threadIdx.x;
    float s = (t < 32) ? bsum[t] : 0.0f;
    #pragma unroll
    for (int m = 1; m < 64; m <<= 1) s += __shfl_xor(s, m);
    if (t == 0) out[0] = s * (1.0f / (float)N_ROWS);
}

extern "C" void kernel_launch(void* const* d_in, const int* in_sizes, int n_in,
                              void* d_out, int out_size, void* d_ws, size_t ws_size,
                              hipStream_t stream) {
    const float* proj1 = (const float*)d_in[0];
    const float* proj2 = (const float*)d_in[1];
    float* out = (float*)d_out;

    char* ws = (char*)d_ws;
    unsigned char* zq = (unsigned char*)ws;                          // 1 MB
    float* partial = (float*)(ws + (size_t)1 * 1024 * 1024);         // 256 KB
    float* posv    = (float*)(ws + (size_t)1536 * 1024);             // 32 KB
    float* bsum    = (float*)(ws + (size_t)1792 * 1024);             // 128 B

    normalize_kernel<<<N_ROWS / 4, 256, 0, stream>>>(proj1, proj2, zq);
    simloss_mfma<<<IBLKS * SEGS, 256, 0, stream>>>(zq, partial, posv);
    rowloss_kernel<<<N_ROWS / 256, 256, 0, stream>>>(partial, posv, bsum);
    final_reduce<<<1, 64, 0, stream>>>(bsum, out);
}

// Round 13
// 36.806 us; speedup vs baseline: 1.0823x; 1.0823x over previous
//
#include <hip/hip_runtime.h>
#include <hip/hip_bf16.h>
#include <math.h>

#define N_ROWS 8192
#define N_HALF 4096
#define D 128
#define SEGS 16
#define IBLKS (N_ROWS / 128)            // 64 i-tiles of 128 rows
#define SEGCOLS (N_ROWS / SEGS)         // 512 cols per block
#define HALVES (SEGCOLS / 64)           // 8 halves of 64 cols
// scale = sqrt(2 * log2(e)): zq_i . zq_j = 2*log2(e)*cos -> exp2(dot) = exp(2*cos)
#define ZSCALE 1.6986437717f
#define LN2 0.69314718056f

typedef __attribute__((ext_vector_type(8))) int   i32x8;   // 32B fp8 fragment
typedef __attribute__((ext_vector_type(4))) int   i32x4;
typedef __attribute__((ext_vector_type(4))) float f32x4;

__device__ __forceinline__ float fast_exp2(float x) {
#if __has_builtin(__builtin_amdgcn_exp2f)
    return __builtin_amdgcn_exp2f(x);
#else
    return exp2f(x);
#endif
}

// ---------------- kernel 1: normalize rows; emit scaled fp8 e4m3 z; zero out ----------------
__global__ __launch_bounds__(256) void normalize_kernel(
    const float* __restrict__ p1, const float* __restrict__ p2,
    unsigned char* __restrict__ zq, float* __restrict__ out)
{
    if (blockIdx.x == 0 && threadIdx.x == 0) out[0] = 0.0f;   // re-zero every launch
    const int row = blockIdx.x * 4 + (threadIdx.x >> 6);
    const int lane = threadIdx.x & 63;
    const float* src = (row < N_HALF) ? (p1 + (size_t)row * D)
                                      : (p2 + (size_t)(row - N_HALF) * D);
    float2 v = ((const float2*)src)[lane];
    float ss = v.x * v.x + v.y * v.y;
    #pragma unroll
    for (int m = 1; m < 64; m <<= 1) ss += __shfl_xor(ss, m);
    float inv = ZSCALE / fmaxf(sqrtf(ss), 1e-12f);
    // pack 2 fp8 (RNE, OCP e4m3): byte0 = k=2*lane, byte1 = k=2*lane+1
    int pk = __builtin_amdgcn_cvt_pk_fp8_f32(v.x * inv, v.y * inv, 0, false);
    ((ushort*)(zq + (size_t)row * D))[lane] = (ushort)(pk & 0xFFFF);
}

// ---------------- kernel 2: dbuf DMA + MX-fp8 K=128 MFMA Gram (R11 structure) ----------------
// Wave-private staging/reads (no main-loop barriers). Half-buffer = 64 cols x
// 128 B = 512 slots of 16B. Slot s: col r = s>>3, chunk c = (s&7)^(r&7).
// Read (col cB, quarter lh): 32B = chunks {2lh, 2lh+1} (same XOR pair).
__global__ __launch_bounds__(256, 2) void simloss_mfma(
    const unsigned char* __restrict__ zq, float* __restrict__ partial,
    float* __restrict__ posv)
{
    __shared__ unsigned char Bs[2][64 * 128];   // 2 x 8 KB
    __shared__ float red[128][4];
    const int t = threadIdx.x;
    const int w = t >> 6;                // wave 0..3 -> 16-col slice of each half
    const int l = t & 63;
    const int l15 = l & 15, lh = l >> 4;
    const int bi = blockIdx.x & (IBLKS - 1);
    const int seg = blockIdx.x >> 6;
    const int iBase = bi * 128;
    const int segBase = seg * SEGCOLS;
    const int pBase = iBase ^ N_HALF;    // partner tile base (128-aligned)

// stage this wave's 16-col slice of one 64x128B half: 2 DMA issues.
#define STAGE(buf, jB)                                                          \
    {                                                                           \
        _Pragma("unroll")                                                       \
        for (int i = 0; i < 2; ++i) {                                           \
            const int s = w * 128 + i * 64 + l;                                 \
            const int r = s >> 3;                                               \
            const int c = (s & 7) ^ (r & 7);                                    \
            const unsigned char* g = zq + (size_t)((jB) + r) * D + c * 16;      \
            unsigned char* lp = (buf) + (size_t)s * 16;                         \
            __builtin_amdgcn_global_load_lds(                                   \
                (const __attribute__((address_space(1))) unsigned int*)g,       \
                (__attribute__((address_space(3))) unsigned int*)lp, 16, 0, 0); \
        }                                                                       \
    }

    STAGE(&Bs[0][0], segBase);           // prologue: half 0 in flight

    // A tile (128 rows x 128 k fp8) in registers: 8 m-tiles x 32 B
    i32x8 a[8];
    #pragma unroll
    for (int m = 0; m < 8; ++m)
        a[m] = *(const i32x8*)(zq + (size_t)(iBase + m * 16 + l15) * D + lh * 32);

    float rs[8][4];
    #pragma unroll
    for (int m = 0; m < 8; ++m)
        #pragma unroll
        for (int r = 0; r < 4; ++r) rs[m][r] = 0.0f;

    const int cB = w * 16 + l15;         // this lane's col within each half
    const int slot0base = cB * 8;

    #pragma unroll 1
    for (int h = 0; h < HALVES; ++h) {
        const int jBase = segBase + h * 64;
        const unsigned char* bufc = &Bs[h & 1][0];

        if (h + 1 < HALVES) {
            STAGE(&Bs[(h + 1) & 1][0], jBase + 64);          // next half in flight
            asm volatile("s_waitcnt vmcnt(2)" ::: "memory"); // current half landed
        } else {
            asm volatile("s_waitcnt vmcnt(0)" ::: "memory");
        }

        const int slot0 = slot0base + ((2 * lh)     ^ (cB & 7));
        const int slot1 = slot0base + ((2 * lh + 1) ^ (cB & 7));
        i32x4 blo = *(const i32x4*)(bufc + slot0 * 16);
        i32x4 bhi = *(const i32x4*)(bufc + slot1 * 16);
        i32x8 bv;
        bv[0] = blo[0]; bv[1] = blo[1]; bv[2] = blo[2]; bv[3] = blo[3];
        bv[4] = bhi[0]; bv[5] = bhi[1]; bv[6] = bhi[2]; bv[7] = bhi[3];

        f32x4 c[8];
        #pragma unroll
        for (int m = 0; m < 8; ++m) { f32x4 z4 = {0.f, 0.f, 0.f, 0.f}; c[m] = z4; }
        #pragma unroll
        for (int m = 0; m < 8; ++m)
            c[m] = __builtin_amdgcn_mfma_scale_f32_16x16x128_f8f6f4(
                       a[m], bv, c[m], 0, 0,           // cbsz=FP8, blgp=FP8
                       0, 0x7F7F7F7Fu,                 // scale A = 2^0
                       0, 0x7F7F7F7Fu);                // scale B = 2^0

        if ((jBase & ~127) == iBase) {   // rare: half covers self-diagonal
            const int sOff = jBase - iBase;          // 0 or 64
            #pragma unroll
            for (int m = 0; m < 8; ++m)
                #pragma unroll
                for (int r = 0; r < 4; ++r) {
                    const int rowLocal = m * 16 + lh * 4 + r;
                    float e = fast_exp2(c[m][r]);
                    rs[m][r] += (rowLocal == sOff + cB) ? 0.0f : e;
                }
        } else {                         // hot path
            #pragma unroll
            for (int m = 0; m < 8; ++m)
                #pragma unroll
                for (int r = 0; r < 4; ++r)
                    rs[m][r] += fast_exp2(c[m][r]);
        }
        if ((jBase & ~127) == pBase) {   // rare: half covers partner diagonal
            const int pOff = jBase - pBase;          // 0 or 64
            #pragma unroll
            for (int m = 0; m < 8; ++m)
                #pragma unroll
                for (int r = 0; r < 4; ++r) {
                    const int rowLocal = m * 16 + lh * 4 + r;
                    if (rowLocal == pOff + cB)
                        posv[iBase + rowLocal] = c[m][r] * LN2;   // = 2*cos
                }
        }
    }
#undef STAGE

    // reduce rs over the 16 cols held across l15 lanes
    #pragma unroll
    for (int m = 0; m < 8; ++m)
        #pragma unroll
        for (int r = 0; r < 4; ++r) {
            float v = rs[m][r];
            v += __shfl_xor(v, 1); v += __shfl_xor(v, 2);
            v += __shfl_xor(v, 4); v += __shfl_xor(v, 8);
            rs[m][r] = v;
        }
    if (l15 == 0) {
        #pragma unroll
        for (int m = 0; m < 8; ++m)
            #pragma unroll
            for (int r = 0; r < 4; ++r)
                red[m * 16 + lh * 4 + r][w] = rs[m][r];
    }
    __syncthreads();                     // real cross-wave reduce: keep
    if (t < 128) {
        float v = red[t][0] + red[t][1] + red[t][2] + red[t][3];
        partial[(size_t)seg * N_ROWS + iBase + t] = v;
    }
}

// ---------------- kernel 3: per-row loss + block sum + atomic into out ----------------
__global__ __launch_bounds__(256) void rowloss_kernel(
    const float* __restrict__ partial, const float* __restrict__ posv,
    float* __restrict__ out)
{
    const int row = blockIdx.x * 256 + threadIdx.x;
    float denom = 0.0f;
    #pragma unroll
    for (int s = 0; s < SEGS; ++s) denom += partial[(size_t)s * N_ROWS + row];
    float loss = logf(denom) - posv[row];
    #pragma unroll
    for (int m = 1; m < 64; m <<= 1) loss += __shfl_xor(loss, m);
    __shared__ float red[4];
    if ((threadIdx.x & 63) == 0) red[threadIdx.x >> 6] = loss;
    __syncthreads();
    if (threadIdx.x == 0)
        atomicAdd(out, (red[0] + red[1] + red[2] + red[3]) * (1.0f / (float)N_ROWS));
}

extern "C" void kernel_launch(void* const* d_in, const int* in_sizes, int n_in,
                              void* d_out, int out_size, void* d_ws, size_t ws_size,
                              hipStream_t stream) {
    const float* proj1 = (const float*)d_in[0];
    const float* proj2 = (const float*)d_in[1];
    float* out = (float*)d_out;

    char* ws = (char*)d_ws;
    unsigned char* zq = (unsigned char*)ws;                          // 1 MB
    float* partial = (float*)(ws + (size_t)1 * 1024 * 1024);         // 512 KB (16 segs)
    float* posv    = (float*)(ws + (size_t)1792 * 1024);             // 32 KB

    normalize_kernel<<<N_ROWS / 4, 256, 0, stream>>>(proj1, proj2, zq, out);
    simloss_mfma<<<IBLKS * SEGS, 256, 0, stream>>>(zq, partial, posv);
    rowloss_kernel<<<N_ROWS / 256, 256, 0, stream>>>(partial, posv, out);
}

// Round 14
// 30.712 us; speedup vs baseline: 1.2970x; 1.1984x over previous
//
#include <hip/hip_runtime.h>
#include <hip/hip_bf16.h>
#include <math.h>

#define N_ROWS 8192
#define N_HALF 4096
#define D 128
#define SEGS 8
#define IBLKS (N_ROWS / 128)            // 64 i-tiles of 128 rows
#define SEGCOLS (N_ROWS / SEGS)         // 1024 cols per block
#define HALVES (SEGCOLS / 64)           // 16 halves of 64 cols
// scale = sqrt(2 * log2(e)): zq_i . zq_j = 2*log2(e)*cos -> exp2(dot) = exp(2*cos)
#define ZSCALE 1.6986437717f
#define LN2 0.69314718056f

typedef __attribute__((ext_vector_type(8))) int   i32x8;   // 32B fp8 fragment
typedef __attribute__((ext_vector_type(4))) int   i32x4;
typedef __attribute__((ext_vector_type(4))) float f32x4;

__device__ __forceinline__ float fast_exp2(float x) {
#if __has_builtin(__builtin_amdgcn_exp2f)
    return __builtin_amdgcn_exp2f(x);
#else
    return exp2f(x);
#endif
}

// ---------------- kernel 1: normalize rows; emit scaled fp8 e4m3 z; zero out ----------------
__global__ __launch_bounds__(256) void normalize_kernel(
    const float* __restrict__ p1, const float* __restrict__ p2,
    unsigned char* __restrict__ zq, float* __restrict__ out)
{
    if (blockIdx.x == 0 && threadIdx.x == 0) out[0] = 0.0f;   // re-zero every launch
    const int row = blockIdx.x * 4 + (threadIdx.x >> 6);
    const int lane = threadIdx.x & 63;
    const float* src = (row < N_HALF) ? (p1 + (size_t)row * D)
                                      : (p2 + (size_t)(row - N_HALF) * D);
    float2 v = ((const float2*)src)[lane];
    float ss = v.x * v.x + v.y * v.y;
    #pragma unroll
    for (int m = 1; m < 64; m <<= 1) ss += __shfl_xor(ss, m);
    float inv = ZSCALE / fmaxf(sqrtf(ss), 1e-12f);
    // pack 2 fp8 (RNE, OCP e4m3): byte0 = k=2*lane, byte1 = k=2*lane+1
    int pk = __builtin_amdgcn_cvt_pk_fp8_f32(v.x * inv, v.y * inv, 0, false);
    ((ushort*)(zq + (size_t)row * D))[lane] = (ushort)(pk & 0xFFFF);
}

// ---------------- kernel 2: 3-buffer 2-deep DMA pipeline + MX-fp8 K=128 MFMA Gram ----------------
// Wave-private staging/reads (no main-loop barriers). Half-buffer = 64 cols x
// 128 B = 512 slots of 16B. Slot s: col r = s>>3, chunk c = (s&7)^(r&7).
// Read (col cB, quarter lh): 32B = chunks {2lh, 2lh+1} (same XOR pair).
__global__ __launch_bounds__(256, 2) void simloss_mfma(
    const unsigned char* __restrict__ zq, float* __restrict__ partial,
    float* __restrict__ posv)
{
    __shared__ unsigned char Bs[3][64 * 128];   // 3 x 8 KB
    __shared__ float red[128][4];
    const int t = threadIdx.x;
    const int w = t >> 6;                // wave 0..3 -> 16-col slice of each half
    const int l = t & 63;
    const int l15 = l & 15, lh = l >> 4;
    const int bi = blockIdx.x & (IBLKS - 1);
    const int seg = blockIdx.x >> 6;
    const int iBase = bi * 128;
    const int segBase = seg * SEGCOLS;
    const int pBase = iBase ^ N_HALF;    // partner tile base (128-aligned)

// stage this wave's 16-col slice of one 64x128B half: 2 DMA issues.
#define STAGE(buf, jB)                                                          \
    {                                                                           \
        _Pragma("unroll")                                                       \
        for (int i = 0; i < 2; ++i) {                                           \
            const int s = w * 128 + i * 64 + l;                                 \
            const int r = s >> 3;                                               \
            const int c = (s & 7) ^ (r & 7);                                    \
            const unsigned char* g = zq + (size_t)((jB) + r) * D + c * 16;      \
            unsigned char* lp = (buf) + (size_t)s * 16;                         \
            __builtin_amdgcn_global_load_lds(                                   \
                (const __attribute__((address_space(1))) unsigned int*)g,       \
                (__attribute__((address_space(3))) unsigned int*)lp, 16, 0, 0); \
        }                                                                       \
    }

    STAGE(&Bs[0][0], segBase);           // prologue: halves 0,1 in flight
    STAGE(&Bs[1][0], segBase + 64);

    // A tile (128 rows x 128 k fp8) in registers: 8 m-tiles x 32 B
    i32x8 a[8];
    #pragma unroll
    for (int m = 0; m < 8; ++m)
        a[m] = *(const i32x8*)(zq + (size_t)(iBase + m * 16 + l15) * D + lh * 32);

    float rs[8][4];
    #pragma unroll
    for (int m = 0; m < 8; ++m)
        #pragma unroll
        for (int r = 0; r < 4; ++r) rs[m][r] = 0.0f;

    const int cB = w * 16 + l15;         // this lane's col within each half
    const int slot0base = cB * 8;

    int bufIdx = 0;                      // rotating buffer index (0,1,2)
    #pragma unroll 1
    for (int h = 0; h < HALVES; ++h) {
        const int jBase = segBase + h * 64;
        const unsigned char* bufc = &Bs[bufIdx][0];
        const int nextBuf = (bufIdx + 2 >= 3) ? bufIdx - 1 : bufIdx + 2;

        if (h + 2 < HALVES) {
            STAGE(&Bs[nextBuf][0], jBase + 128);             // h+2 in flight
            asm volatile("s_waitcnt vmcnt(4)" ::: "memory"); // h landed (h+1,h+2 fly)
        } else if (h + 1 < HALVES) {
            asm volatile("s_waitcnt vmcnt(2)" ::: "memory"); // h landed (h+1 flies)
        } else {
            asm volatile("s_waitcnt vmcnt(0)" ::: "memory");
        }

        const int slot0 = slot0base + ((2 * lh)     ^ (cB & 7));
        const int slot1 = slot0base + ((2 * lh + 1) ^ (cB & 7));
        i32x4 blo = *(const i32x4*)(bufc + slot0 * 16);
        i32x4 bhi = *(const i32x4*)(bufc + slot1 * 16);
        i32x8 bv;
        bv[0] = blo[0]; bv[1] = blo[1]; bv[2] = blo[2]; bv[3] = blo[3];
        bv[4] = bhi[0]; bv[5] = bhi[1]; bv[6] = bhi[2]; bv[7] = bhi[3];

        f32x4 c[8];
        #pragma unroll
        for (int m = 0; m < 8; ++m) { f32x4 z4 = {0.f, 0.f, 0.f, 0.f}; c[m] = z4; }
        #pragma unroll
        for (int m = 0; m < 8; ++m)
            c[m] = __builtin_amdgcn_mfma_scale_f32_16x16x128_f8f6f4(
                       a[m], bv, c[m], 0, 0,           // cbsz=FP8, blgp=FP8
                       0, 0x7F7F7F7Fu,                 // scale A = 2^0
                       0, 0x7F7F7F7Fu);                // scale B = 2^0

        if ((jBase & ~127) == iBase) {   // rare: half covers self-diagonal
            const int sOff = jBase - iBase;          // 0 or 64
            #pragma unroll
            for (int m = 0; m < 8; ++m)
                #pragma unroll
                for (int r = 0; r < 4; ++r) {
                    const int rowLocal = m * 16 + lh * 4 + r;
                    float e = fast_exp2(c[m][r]);
                    rs[m][r] += (rowLocal == sOff + cB) ? 0.0f : e;
                }
        } else {                         // hot path
            #pragma unroll
            for (int m = 0; m < 8; ++m)
                #pragma unroll
                for (int r = 0; r < 4; ++r)
                    rs[m][r] += fast_exp2(c[m][r]);
        }
        if ((jBase & ~127) == pBase) {   // rare: half covers partner diagonal
            const int pOff = jBase - pBase;          // 0 or 64
            #pragma unroll
            for (int m = 0; m < 8; ++m)
                #pragma unroll
                for (int r = 0; r < 4; ++r) {
                    const int rowLocal = m * 16 + lh * 4 + r;
                    if (rowLocal == pOff + cB)
                        posv[iBase + rowLocal] = c[m][r] * LN2;   // = 2*cos
                }
        }

        bufIdx = (bufIdx + 1 >= 3) ? 0 : bufIdx + 1;
    }
#undef STAGE

    // reduce rs over the 16 cols held across l15 lanes
    #pragma unroll
    for (int m = 0; m < 8; ++m)
        #pragma unroll
        for (int r = 0; r < 4; ++r) {
            float v = rs[m][r];
            v += __shfl_xor(v, 1); v += __shfl_xor(v, 2);
            v += __shfl_xor(v, 4); v += __shfl_xor(v, 8);
            rs[m][r] = v;
        }
    if (l15 == 0) {
        #pragma unroll
        for (int m = 0; m < 8; ++m)
            #pragma unroll
            for (int r = 0; r < 4; ++r)
                red[m * 16 + lh * 4 + r][w] = rs[m][r];
    }
    __syncthreads();                     // real cross-wave reduce: keep
    if (t < 128) {
        float v = red[t][0] + red[t][1] + red[t][2] + red[t][3];
        partial[(size_t)seg * N_ROWS + iBase + t] = v;
    }
}

// ---------------- kernel 3: per-row loss + block sum + atomic into out ----------------
__global__ __launch_bounds__(256) void rowloss_kernel(
    const float* __restrict__ partial, const float* __restrict__ posv,
    float* __restrict__ out)
{
    const int row = blockIdx.x * 256 + threadIdx.x;
    float denom = 0.0f;
    #pragma unroll
    for (int s = 0; s < SEGS; ++s) denom += partial[(size_t)s * N_ROWS + row];
    float loss = logf(denom) - posv[row];
    #pragma unroll
    for (int m = 1; m < 64; m <<= 1) loss += __shfl_xor(loss, m);
    __shared__ float red[4];
    if ((threadIdx.x & 63) == 0) red[threadIdx.x >> 6] = loss;
    __syncthreads();
    if (threadIdx.x == 0)
        atomicAdd(out, (red[0] + red[1] + red[2] + red[3]) * (1.0f / (float)N_ROWS));
}

extern "C" void kernel_launch(void* const* d_in, const int* in_sizes, int n_in,
                              void* d_out, int out_size, void* d_ws, size_t ws_size,
                              hipStream_t stream) {
    const float* proj1 = (const float*)d_in[0];
    const float* proj2 = (const float*)d_in[1];
    float* out = (float*)d_out;

    char* ws = (char*)d_ws;
    unsigned char* zq = (unsigned char*)ws;                          // 1 MB
    float* partial = (float*)(ws + (size_t)1 * 1024 * 1024);         // 256 KB
    float* posv    = (float*)(ws + (size_t)1792 * 1024);             // 32 KB

    normalize_kernel<<<N_ROWS / 4, 256, 0, stream>>>(proj1, proj2, zq, out);
    simloss_mfma<<<IBLKS * SEGS, 256, 0, stream>>>(zq, partial, posv);
    rowloss_kernel<<<N_ROWS / 256, 256, 0, stream>>>(partial, posv, out);
}

// Round 15
// 29.530 us; speedup vs baseline: 1.3489x; 1.0400x over previous
//
#include <hip/hip_runtime.h>
#include <hip/hip_bf16.h>
#include <math.h>

#define N_ROWS 8192
#define N_HALF 4096
#define D 128
#define SEGS 8
#define IBLKS (N_ROWS / 128)            // 64 i-tiles of 128 rows
#define SEGCOLS (N_ROWS / SEGS)         // 1024 cols per block
#define PAIRS (SEGCOLS / 128)           // 8 pairs of 64-col halves
// scale = sqrt(2 * log2(e)): zq_i . zq_j = 2*log2(e)*cos -> exp2(dot) = exp(2*cos)
#define ZSCALE 1.6986437717f
#define LN2 0.69314718056f

typedef __attribute__((ext_vector_type(8))) int   i32x8;   // 32B fp8 fragment
typedef __attribute__((ext_vector_type(4))) int   i32x4;
typedef __attribute__((ext_vector_type(4))) float f32x4;

__device__ __forceinline__ float fast_exp2(float x) {
#if __has_builtin(__builtin_amdgcn_exp2f)
    return __builtin_amdgcn_exp2f(x);
#else
    return exp2f(x);
#endif
}

// ---------------- kernel 1: normalize rows; emit scaled fp8 e4m3 z; zero out ----------------
__global__ __launch_bounds__(256) void normalize_kernel(
    const float* __restrict__ p1, const float* __restrict__ p2,
    unsigned char* __restrict__ zq, float* __restrict__ out)
{
    if (blockIdx.x == 0 && threadIdx.x == 0) out[0] = 0.0f;   // re-zero every launch
    const int row = blockIdx.x * 4 + (threadIdx.x >> 6);
    const int lane = threadIdx.x & 63;
    const float* src = (row < N_HALF) ? (p1 + (size_t)row * D)
                                      : (p2 + (size_t)(row - N_HALF) * D);
    float2 v = ((const float2*)src)[lane];
    float ss = v.x * v.x + v.y * v.y;
    #pragma unroll
    for (int m = 1; m < 64; m <<= 1) ss += __shfl_xor(ss, m);
    float inv = ZSCALE / fmaxf(sqrtf(ss), 1e-12f);
    // pack 2 fp8 (RNE, OCP e4m3): byte0 = k=2*lane, byte1 = k=2*lane+1
    int pk = __builtin_amdgcn_cvt_pk_fp8_f32(v.x * inv, v.y * inv, 0, false);
    ((ushort*)(zq + (size_t)row * D))[lane] = (ushort)(pk & 0xFFFF);
}

// ---------------- kernel 2: pair-interleaved dbuf DMA + MX-fp8 K=128 MFMA Gram ----------------
// Wave-private staging/reads, no main-loop barriers. Two 64-col halves are
// processed per iteration with independent register chains (2x ILP per wave).
// Half-buffer = 512 slots of 16B. Slot s: col r = s>>3, chunk c = (s&7)^(r&7).
__global__ __launch_bounds__(256, 2) void simloss_mfma(
    const unsigned char* __restrict__ zq, float* __restrict__ partial,
    float* __restrict__ posv)
{
    __shared__ unsigned char Bs[4][64 * 128];   // 4 x 8 KB (2 pairs)
    __shared__ float red[128][4];
    const int t = threadIdx.x;
    const int w = t >> 6;                // wave 0..3 -> 16-col slice of each half
    const int l = t & 63;
    const int l15 = l & 15, lh = l >> 4;
    const int bi = blockIdx.x & (IBLKS - 1);
    const int seg = blockIdx.x >> 6;
    const int iBase = bi * 128;
    const int segBase = seg * SEGCOLS;
    const int pBase = iBase ^ N_HALF;    // partner tile base (128-aligned)

// stage this wave's 16-col slice of one 64x128B half: 2 DMA issues.
#define STAGE(buf, jB)                                                          \
    {                                                                           \
        _Pragma("unroll")                                                       \
        for (int i = 0; i < 2; ++i) {                                           \
            const int s = w * 128 + i * 64 + l;                                 \
            const int r = s >> 3;                                               \
            const int c = (s & 7) ^ (r & 7);                                    \
            const unsigned char* g = zq + (size_t)((jB) + r) * D + c * 16;      \
            unsigned char* lp = (buf) + (size_t)s * 16;                         \
            __builtin_amdgcn_global_load_lds(                                   \
                (const __attribute__((address_space(1))) unsigned int*)g,       \
                (__attribute__((address_space(3))) unsigned int*)lp, 16, 0, 0); \
        }                                                                       \
    }

// per-half epilogue: row-sum exps with rare diagonal/positive handling
#define EPILOGUE(cA, jB)                                                        \
    {                                                                           \
        if (((jB) & ~127) == iBase) {                                           \
            const int sOff = (jB) - iBase;                                      \
            _Pragma("unroll")                                                   \
            for (int m = 0; m < 8; ++m)                                         \
                _Pragma("unroll")                                               \
                for (int r = 0; r < 4; ++r) {                                   \
                    const int rowLocal = m * 16 + lh * 4 + r;                   \
                    float e = fast_exp2(cA[m][r]);                              \
                    rs[m][r] += (rowLocal == sOff + cB) ? 0.0f : e;             \
                }                                                               \
        } else {                                                                \
            _Pragma("unroll")                                                   \
            for (int m = 0; m < 8; ++m)                                         \
                _Pragma("unroll")                                               \
                for (int r = 0; r < 4; ++r)                                     \
                    rs[m][r] += fast_exp2(cA[m][r]);                            \
        }                                                                       \
        if (((jB) & ~127) == pBase) {                                           \
            const int pOff = (jB) - pBase;                                      \
            _Pragma("unroll")                                                   \
            for (int m = 0; m < 8; ++m)                                         \
                _Pragma("unroll")                                               \
                for (int r = 0; r < 4; ++r) {                                   \
                    const int rowLocal = m * 16 + lh * 4 + r;                   \
                    if (rowLocal == pOff + cB)                                  \
                        posv[iBase + rowLocal] = cA[m][r] * LN2;                \
                }                                                               \
        }                                                                       \
    }

    STAGE(&Bs[0][0], segBase);           // prologue: pair 0 in flight
    STAGE(&Bs[1][0], segBase + 64);

    // A tile (128 rows x 128 k fp8) in registers: 8 m-tiles x 32 B
    i32x8 a[8];
    #pragma unroll
    for (int m = 0; m < 8; ++m)
        a[m] = *(const i32x8*)(zq + (size_t)(iBase + m * 16 + l15) * D + lh * 32);

    float rs[8][4];
    #pragma unroll
    for (int m = 0; m < 8; ++m)
        #pragma unroll
        for (int r = 0; r < 4; ++r) rs[m][r] = 0.0f;

    const int cB = w * 16 + l15;         // this lane's col within each half
    const int slot0base = cB * 8;
    const int sl0 = slot0base + ((2 * lh)     ^ (cB & 7));
    const int sl1 = slot0base + ((2 * lh + 1) ^ (cB & 7));

    #pragma unroll 1
    for (int p = 0; p < PAIRS; ++p) {
        const int jB0 = segBase + p * 128;
        const int jB1 = jB0 + 64;
        const unsigned char* buf0 = &Bs[(p & 1) * 2][0];
        const unsigned char* buf1 = &Bs[(p & 1) * 2 + 1][0];

        if (p + 1 < PAIRS) {             // next pair in flight (4 DMAs)
            STAGE(&Bs[((p + 1) & 1) * 2][0],     jB1 + 64);
            STAGE(&Bs[((p + 1) & 1) * 2 + 1][0], jB1 + 128);
            asm volatile("s_waitcnt vmcnt(4)" ::: "memory");  // pair p landed
        } else {
            asm volatile("s_waitcnt vmcnt(0)" ::: "memory");
        }

        // ds_reads for BOTH halves up front (4 independent b128 reads)
        i32x4 b0lo = *(const i32x4*)(buf0 + sl0 * 16);
        i32x4 b0hi = *(const i32x4*)(buf0 + sl1 * 16);
        i32x4 b1lo = *(const i32x4*)(buf1 + sl0 * 16);
        i32x4 b1hi = *(const i32x4*)(buf1 + sl1 * 16);
        i32x8 bv0, bv1;
        bv0[0] = b0lo[0]; bv0[1] = b0lo[1]; bv0[2] = b0lo[2]; bv0[3] = b0lo[3];
        bv0[4] = b0hi[0]; bv0[5] = b0hi[1]; bv0[6] = b0hi[2]; bv0[7] = b0hi[3];
        bv1[0] = b1lo[0]; bv1[1] = b1lo[1]; bv1[2] = b1lo[2]; bv1[3] = b1lo[3];
        bv1[4] = b1hi[0]; bv1[5] = b1hi[1]; bv1[6] = b1hi[2]; bv1[7] = b1hi[3];

        f32x4 c0[8], c1[8];
        #pragma unroll
        for (int m = 0; m < 8; ++m) {
            f32x4 z4 = {0.f, 0.f, 0.f, 0.f};
            c0[m] = z4; c1[m] = z4;
        }
        // 16 interleaved independent MFMAs
        #pragma unroll
        for (int m = 0; m < 8; ++m) {
            c0[m] = __builtin_amdgcn_mfma_scale_f32_16x16x128_f8f6f4(
                        a[m], bv0, c0[m], 0, 0, 0, 0x7F7F7F7Fu, 0, 0x7F7F7F7Fu);
            c1[m] = __builtin_amdgcn_mfma_scale_f32_16x16x128_f8f6f4(
                        a[m], bv1, c1[m], 0, 0, 0, 0x7F7F7F7Fu, 0, 0x7F7F7F7Fu);
        }

        EPILOGUE(c0, jB0);
        EPILOGUE(c1, jB1);
    }
#undef STAGE
#undef EPILOGUE

    // reduce rs over the 16 cols held across l15 lanes
    #pragma unroll
    for (int m = 0; m < 8; ++m)
        #pragma unroll
        for (int r = 0; r < 4; ++r) {
            float v = rs[m][r];
            v += __shfl_xor(v, 1); v += __shfl_xor(v, 2);
            v += __shfl_xor(v, 4); v += __shfl_xor(v, 8);
            rs[m][r] = v;
        }
    if (l15 == 0) {
        #pragma unroll
        for (int m = 0; m < 8; ++m)
            #pragma unroll
            for (int r = 0; r < 4; ++r)
                red[m * 16 + lh * 4 + r][w] = rs[m][r];
    }
    __syncthreads();                     // real cross-wave reduce: keep
    if (t < 128) {
        float v = red[t][0] + red[t][1] + red[t][2] + red[t][3];
        partial[(size_t)seg * N_ROWS + iBase + t] = v;
    }
}

// ---------------- kernel 3: per-row loss + block sum + atomic into out ----------------
__global__ __launch_bounds__(256) void rowloss_kernel(
    const float* __restrict__ partial, const float* __restrict__ posv,
    float* __restrict__ out)
{
    const int row = blockIdx.x * 256 + threadIdx.x;
    float denom = 0.0f;
    #pragma unroll
    for (int s = 0; s < SEGS; ++s) denom += partial[(size_t)s * N_ROWS + row];
    float loss = logf(denom) - posv[row];
    #pragma unroll
    for (int m = 1; m < 64; m <<= 1) loss += __shfl_xor(loss, m);
    __shared__ float red[4];
    if ((threadIdx.x & 63) == 0) red[threadIdx.x >> 6] = loss;
    __syncthreads();
    if (threadIdx.x == 0)
        atomicAdd(out, (red[0] + red[1] + red[2] + red[3]) * (1.0f / (float)N_ROWS));
}

extern "C" void kernel_launch(void* const* d_in, const int* in_sizes, int n_in,
                              void* d_out, int out_size, void* d_ws, size_t ws_size,
                              hipStream_t stream) {
    const float* proj1 = (const float*)d_in[0];
    const float* proj2 = (const float*)d_in[1];
    float* out = (float*)d_out;

    char* ws = (char*)d_ws;
    unsigned char* zq = (unsigned char*)ws;                          // 1 MB
    float* partial = (float*)(ws + (size_t)1 * 1024 * 1024);         // 256 KB
    float* posv    = (float*)(ws + (size_t)1792 * 1024);             // 32 KB

    normalize_kernel<<<N_ROWS / 4, 256, 0, stream>>>(proj1, proj2, zq, out);
    simloss_mfma<<<IBLKS * SEGS, 256, 0, stream>>>(zq, partial, posv);
    rowloss_kernel<<<N_ROWS / 256, 256, 0, stream>>>(partial, posv, out);
}

// Round 16
// 27.039 us; speedup vs baseline: 1.4732x; 1.0921x over previous
//
#include <hip/hip_runtime.h>
#include <hip/hip_bf16.h>
#include <math.h>

#define N_ROWS 8192
#define N_HALF 4096
#define D 128
#define NTILES 64
// scale = sqrt(2 * log2(e)): zq_i . zq_j = 2*log2(e)*cos -> exp2(dot) = exp(2*cos)
#define ZSCALE 1.6986437717f
#define LN2 0.69314718056f

typedef __attribute__((ext_vector_type(8))) int   i32x8;   // 32B fp8 fragment
typedef __attribute__((ext_vector_type(4))) int   i32x4;
typedef __attribute__((ext_vector_type(4))) float f32x4;

__device__ __forceinline__ float fast_exp2(float x) {
#if __has_builtin(__builtin_amdgcn_exp2f)
    return __builtin_amdgcn_exp2f(x);
#else
    return exp2f(x);
#endif
}

// ---------------- kernel 1: normalize; emit fp8 e4m3 z; zero denom + out ----------------
__global__ __launch_bounds__(256) void normalize_kernel(
    const float* __restrict__ p1, const float* __restrict__ p2,
    unsigned char* __restrict__ zq, float* __restrict__ denom,
    float* __restrict__ out)
{
    if (blockIdx.x < 32) denom[blockIdx.x * 256 + threadIdx.x] = 0.0f;  // re-zero
    if (blockIdx.x == 0 && threadIdx.x == 0) out[0] = 0.0f;
    const int row = blockIdx.x * 4 + (threadIdx.x >> 6);
    const int lane = threadIdx.x & 63;
    const float* src = (row < N_HALF) ? (p1 + (size_t)row * D)
                                      : (p2 + (size_t)(row - N_HALF) * D);
    float2 v = ((const float2*)src)[lane];
    float ss = v.x * v.x + v.y * v.y;
    #pragma unroll
    for (int m = 1; m < 64; m <<= 1) ss += __shfl_xor(ss, m);
    float inv = ZSCALE / fmaxf(sqrtf(ss), 1e-12f);
    int pk = __builtin_amdgcn_cvt_pk_fp8_f32(v.x * inv, v.y * inv, 0, false);
    ((ushort*)(zq + (size_t)row * D))[lane] = (ushort)(pk & 0xFFFF);
}

// ---------------- kernel 2: symmetric MX-fp8 Gram, dual-credit, R15 pipeline ----------------
// Block (bi, blk): i-tile bi, j-tiles d = blk*4 .. (+3 or +4 for blk==7), j = (bi+d)&63.
// d==0: diag (row credit, self-excluded). d==32: partner tile, computed by both
// endpoints, row credit only (covers both sides), posv extracted. 1<=d<=31: dual
// credit (rows via rs, cols via shfl-reduced stash -> atomics at end).
__global__ __launch_bounds__(256, 2) void simloss_sym(
    const unsigned char* __restrict__ zq, float* __restrict__ denom,
    float* __restrict__ posv)
{
    __shared__ unsigned char Bs[4][64 * 128];   // 4 x 8 KB (2 tiles in flight)
    __shared__ float red[128][4];
    __shared__ float colLds[5][128];
    const int t = threadIdx.x;
    const int w = t >> 6;
    const int l = t & 63;
    const int l15 = l & 15, lh = l >> 4;
    const int bi  = blockIdx.x & 63;
    const int blk = blockIdx.x >> 6;            // 0..7
    const int iBase = bi * 128;
    const int d0 = blk * 4;
    const int nT = (blk == 7) ? 5 : 4;

// stage this wave's 16-col slice of one 64x128B half: 2 DMA issues.
#define STAGE(buf, jB)                                                          \
    {                                                                           \
        _Pragma("unroll")                                                       \
        for (int i = 0; i < 2; ++i) {                                           \
            const int s = w * 128 + i * 64 + l;                                 \
            const int r = s >> 3;                                               \
            const int c = (s & 7) ^ (r & 7);                                    \
            const unsigned char* g = zq + (size_t)((jB) + r) * D + c * 16;      \
            unsigned char* lp = (buf) + (size_t)s * 16;                         \
            __builtin_amdgcn_global_load_lds(                                   \
                (const __attribute__((address_space(1))) unsigned int*)g,       \
                (__attribute__((address_space(3))) unsigned int*)lp, 16, 0, 0); \
        }                                                                       \
    }

    {   // prologue: tile d0's two halves in flight
        const int jB = ((bi + d0) & 63) * 128;
        STAGE(&Bs[0][0], jB);
        STAGE(&Bs[1][0], jB + 64);
    }

    // A tile (128 rows x 128 k fp8) in registers
    i32x8 a[8];
    #pragma unroll
    for (int m = 0; m < 8; ++m)
        a[m] = *(const i32x8*)(zq + (size_t)(iBase + m * 16 + l15) * D + lh * 32);

    float rs[8][4];
    #pragma unroll
    for (int m = 0; m < 8; ++m)
        #pragma unroll
        for (int r = 0; r < 4; ++r) rs[m][r] = 0.0f;

    const int cB = w * 16 + l15;
    const int slot0base = cB * 8;
    const int sl0 = slot0base + ((2 * lh)     ^ (cB & 7));
    const int sl1 = slot0base + ((2 * lh + 1) ^ (cB & 7));

    #pragma unroll 1
    for (int ts = 0; ts < nT; ++ts) {
        const int dcur = d0 + ts;
        const unsigned char* buf0 = &Bs[(ts & 1) * 2][0];
        const unsigned char* buf1 = &Bs[(ts & 1) * 2 + 1][0];

        if (ts + 1 < nT) {               // next tile's halves in flight (4 DMAs)
            const int jn = ((bi + dcur + 1) & 63) * 128;
            STAGE(&Bs[((ts + 1) & 1) * 2][0],     jn);
            STAGE(&Bs[((ts + 1) & 1) * 2 + 1][0], jn + 64);
            asm volatile("s_waitcnt vmcnt(4)" ::: "memory");  // current tile landed
        } else {
            asm volatile("s_waitcnt vmcnt(0)" ::: "memory");
        }

        // ds_reads for both halves (4 independent b128)
        i32x4 b0lo = *(const i32x4*)(buf0 + sl0 * 16);
        i32x4 b0hi = *(const i32x4*)(buf0 + sl1 * 16);
        i32x4 b1lo = *(const i32x4*)(buf1 + sl0 * 16);
        i32x4 b1hi = *(const i32x4*)(buf1 + sl1 * 16);
        i32x8 bv0, bv1;
        bv0[0] = b0lo[0]; bv0[1] = b0lo[1]; bv0[2] = b0lo[2]; bv0[3] = b0lo[3];
        bv0[4] = b0hi[0]; bv0[5] = b0hi[1]; bv0[6] = b0hi[2]; bv0[7] = b0hi[3];
        bv1[0] = b1lo[0]; bv1[1] = b1lo[1]; bv1[2] = b1lo[2]; bv1[3] = b1lo[3];
        bv1[4] = b1hi[0]; bv1[5] = b1hi[1]; bv1[6] = b1hi[2]; bv1[7] = b1hi[3];

        f32x4 c0[8], c1[8];
        #pragma unroll
        for (int m = 0; m < 8; ++m) {
            f32x4 z4 = {0.f, 0.f, 0.f, 0.f};
            c0[m] = z4; c1[m] = z4;
        }
        #pragma unroll
        for (int m = 0; m < 8; ++m) {    // 16 interleaved independent MFMAs
            c0[m] = __builtin_amdgcn_mfma_scale_f32_16x16x128_f8f6f4(
                        a[m], bv0, c0[m], 0, 0, 0, 0x7F7F7F7Fu, 0, 0x7F7F7F7Fu);
            c1[m] = __builtin_amdgcn_mfma_scale_f32_16x16x128_f8f6f4(
                        a[m], bv1, c1[m], 0, 0, 0, 0x7F7F7F7Fu, 0, 0x7F7F7F7Fu);
        }

        if (dcur == 0) {                 // diag tile: row credit, self-excluded
            #pragma unroll
            for (int m = 0; m < 8; ++m)
                #pragma unroll
                for (int r = 0; r < 4; ++r) {
                    const int rowLocal = m * 16 + lh * 4 + r;
                    float e0 = fast_exp2(c0[m][r]);
                    float e1 = fast_exp2(c1[m][r]);
                    rs[m][r] += (rowLocal == cB)      ? 0.0f : e0;
                    rs[m][r] += (rowLocal == 64 + cB) ? 0.0f : e1;
                }
        } else if (dcur == 32) {         // partner tile: row credit + posv
            #pragma unroll
            for (int m = 0; m < 8; ++m)
                #pragma unroll
                for (int r = 0; r < 4; ++r) {
                    const int rowLocal = m * 16 + lh * 4 + r;
                    rs[m][r] += fast_exp2(c0[m][r]) + fast_exp2(c1[m][r]);
                    if (rowLocal == cB)      posv[iBase + rowLocal] = c0[m][r] * LN2;
                    if (rowLocal == 64 + cB) posv[iBase + rowLocal] = c1[m][r] * LN2;
                }
        } else {                         // dual credit: rows + cols (symmetry)
            float cs0 = 0.0f, cs1 = 0.0f;
            #pragma unroll
            for (int m = 0; m < 8; ++m)
                #pragma unroll
                for (int r = 0; r < 4; ++r) {
                    float e0 = fast_exp2(c0[m][r]);
                    float e1 = fast_exp2(c1[m][r]);
                    rs[m][r] += e0 + e1;
                    cs0 += e0; cs1 += e1;
                }
            cs0 += __shfl_xor(cs0, 16); cs0 += __shfl_xor(cs0, 32);
            cs1 += __shfl_xor(cs1, 16); cs1 += __shfl_xor(cs1, 32);
            if (l < 16) {                // lh==0 lanes hold full col sums
                colLds[ts][cB] = cs0;
                colLds[ts][64 + cB] = cs1;
            }
        }
    }
#undef STAGE

    // row path: reduce rs over the 16 cols held across l15 lanes
    #pragma unroll
    for (int m = 0; m < 8; ++m)
        #pragma unroll
        for (int r = 0; r < 4; ++r) {
            float v = rs[m][r];
            v += __shfl_xor(v, 1); v += __shfl_xor(v, 2);
            v += __shfl_xor(v, 4); v += __shfl_xor(v, 8);
            rs[m][r] = v;
        }
    if (l15 == 0) {
        #pragma unroll
        for (int m = 0; m < 8; ++m)
            #pragma unroll
            for (int r = 0; r < 4; ++r)
                red[m * 16 + lh * 4 + r][w] = rs[m][r];
    }
    __syncthreads();
    if (t < 128) {
        float v = red[t][0] + red[t][1] + red[t][2] + red[t][3];
        atomicAdd(&denom[iBase + t], v);
    }
    // col path flush
    for (int e = t; e < nT * 128; e += 256) {
        const int ts = e >> 7, col = e & 127;
        const int dd = d0 + ts;
        if (dd != 0 && dd != 32) {
            const int jt = (bi + dd) & 63;
            atomicAdd(&denom[jt * 128 + col], colLds[ts][col]);
        }
    }
}

// ---------------- kernel 3: per-row loss + block sum + atomic into out ----------------
__global__ __launch_bounds__(256) void rowloss_kernel(
    const float* __restrict__ denom, const float* __restrict__ posv,
    float* __restrict__ out)
{
    const int row = blockIdx.x * 256 + threadIdx.x;
    float loss = logf(denom[row]) - posv[row];
    #pragma unroll
    for (int m = 1; m < 64; m <<= 1) loss += __shfl_xor(loss, m);
    __shared__ float red[4];
    if ((threadIdx.x & 63) == 0) red[threadIdx.x >> 6] = loss;
    __syncthreads();
    if (threadIdx.x == 0)
        atomicAdd(out, (red[0] + red[1] + red[2] + red[3]) * (1.0f / (float)N_ROWS));
}

extern "C" void kernel_launch(void* const* d_in, const int* in_sizes, int n_in,
                              void* d_out, int out_size, void* d_ws, size_t ws_size,
                              hipStream_t stream) {
    const float* proj1 = (const float*)d_in[0];
    const float* proj2 = (const float*)d_in[1];
    float* out = (float*)d_out;

    char* ws = (char*)d_ws;
    unsigned char* zq = (unsigned char*)ws;                          // 1 MB
    float* denom = (float*)(ws + (size_t)1 * 1024 * 1024);           // 32 KB
    float* posv  = (float*)(ws + (size_t)1 * 1024 * 1024 + 256 * 1024);  // 32 KB

    normalize_kernel<<<N_ROWS / 4, 256, 0, stream>>>(proj1, proj2, zq, denom, out);
    simloss_sym<<<NTILES * 8, 256, 0, stream>>>(zq, denom, posv);
    rowloss_kernel<<<N_ROWS / 256, 256, 0, stream>>>(denom, posv, out);
}